// Round 6
// baseline (1209.659 us; speedup 1.0000x reference)
//
#include <hip/hip_runtime.h>

// DeepPoly backsubstitution, MI355X. Round 6: f16-split MFMA, BK=32 (32 KB LDS),
// split-K x6 -> grid 768 = 3 blocks/CU co-resident (occupancy was the 2-phase limiter).
// K/split = 1024 = exactly one concat segment -> no segment switching (NSPLIT=6).
// Counted vmcnt(4) + raw barriers kept from round 5.

#define DD 1024
#define LL 16

typedef _Float16 f16x8 __attribute__((ext_vector_type(8)));
typedef _Float16 f16x4 __attribute__((ext_vector_type(4)));
typedef float f32x4 __attribute__((ext_vector_type(4)));

__device__ __forceinline__ void gload16(const void* gsrc, void* ldst) {
  __builtin_amdgcn_global_load_lds(
      (const __attribute__((address_space(1))) unsigned int*)gsrc,
      (__attribute__((address_space(3))) unsigned int*)ldst, 16, 0, 0);
}

struct GemmTabs {
  const _Float16* xs[2][6];
  const _Float16* as[2][6];
};

// ---------------- MFMA GEMM step: out[slab] = (X-planes @ A-planes) partials ----------------
// 128x128 tile, BK=32, 4 waves (2x2, 64x64 each). 16 fragments staged/iter (4 per wave).
template<int NSPLIT>
__global__ __launch_bounds__(256)
void gemm_step(GemmTabs tabs, float* __restrict__ part)
{
  constexpr int KSPL = 6144 / NSPLIT;    // 1024 (NS=6) or 1536 (NS=4)
  constexpr int NIT  = KSPL / 32;        // 32 or 48
  constexpr int NZ   = 2 * NSPLIT;

  __shared__ _Float16 smX[2][8][512];    // [buf][mf][512]  16 KB
  __shared__ _Float16 smA[2][8][512];    // [buf][nf][512]  16 KB

  const int tid  = threadIdx.x;
  const int w    = tid >> 6;
  const int lane = tid & 63;
  const int ln15 = lane & 15;
  const int lhi  = lane >> 4;

  // XCD-local remap: hardware round-robins linear id across 8 XCDs; zz = lin % NZ
  // keeps each z slice's blocks on 1-2 XCDs (L2 reuse of its X/A K-window).
  const int lin = blockIdx.x + gridDim.x * (blockIdx.y + gridDim.y * blockIdx.z);
  const int zz  = lin % NZ;
  const int ij  = lin / NZ;              // 0..63
  const int j0  = (ij & 7) * 128;
  const int i0  = (ij >> 3) * 128;
  const int lu    = zz >> (NSPLIT == 6 ? 0 : 0) ? 0 : 0;  // placeholder (computed below)
  const int lu_   = zz / NSPLIT;         // 0: lower, 1: upper
  const int split = zz % NSPLIT;

  const _Float16* const* xtab = tabs.xs[lu_];
  const _Float16* const* atab = tabs.as[lu_];

  const int wm = w >> 1, wn = w & 1;

  const int kbase = split * KSPL;
  const int seg0  = kbase >> 10;
  const int segB_ = (seg0 + 1 < 6) ? seg0 + 1 : 5;
  const int it_sw = (((seg0 + 1) << 10) - kbase) >> 5;   // >= NIT means never
  const _Float16* xpA = xtab[seg0];
  const _Float16* apA = atab[seg0];
  const _Float16* xpB = xtab[segB_];
  const _Float16* apB = atab[segB_];

  f32x4 acc[4][4];
#pragma unroll
  for (int a = 0; a < 4; ++a)
#pragma unroll
    for (int b = 0; b < 4; ++b) acc[a][b] = (f32x4){0.f, 0.f, 0.f, 0.f};

  const int b_it = (4096 - kbase) >> 5;  // scale-group boundary iteration

  auto stage = [&](int buf, int it) {
    const _Float16* xp = (it < it_sw) ? xpA : xpB;
    const _Float16* ap = (it < it_sw) ? apA : apB;
    const int kcol = ((kbase + it * 32) & 1023) + lhi * 8;
#pragma unroll
    for (int r = 0; r < 4; ++r) {
      const int f = r * 4 + w;           // 0..15, wave-uniform
      if (f < 8)
        gload16(xp + (size_t)(i0 + f * 16 + ln15) * DD + kcol, &smX[buf][f & 7][0]);
      else
        gload16(ap + (size_t)(j0 + (f - 8) * 16 + ln15) * DD + kcol, &smA[buf][f & 7][0]);
    }
  };

  stage(0, 0);                           // 4 loads in flight per wave

  int buf = 0;
  for (int it = 0; it < NIT; ++it) {
    if (it + 1 < NIT) {
      stage(buf ^ 1, it + 1);            // +4 per wave (next tile)
      asm volatile("s_waitcnt vmcnt(4)" ::: "memory");   // cur tile landed (this wave)
    } else {
      asm volatile("s_waitcnt vmcnt(0)" ::: "memory");
    }
    __builtin_amdgcn_s_barrier();        // cur tile landed (all waves)
    __builtin_amdgcn_sched_barrier(0);

    if (it == b_it) {                    // scaled group done: acc *= 2^-11
#pragma unroll
      for (int a = 0; a < 4; ++a)
#pragma unroll
        for (int b = 0; b < 4; ++b) acc[a][b] *= (1.f / 2048.f);
    }

    f16x8 xf[4], af[4];
#pragma unroll
    for (int mi = 0; mi < 4; ++mi)
      xf[mi] = *(const f16x8*)&smX[buf][wm * 4 + mi][lane * 8];
#pragma unroll
    for (int ni = 0; ni < 4; ++ni)
      af[ni] = *(const f16x8*)&smA[buf][wn * 4 + ni][lane * 8];
#pragma unroll
    for (int mi = 0; mi < 4; ++mi)
#pragma unroll
      for (int ni = 0; ni < 4; ++ni)
        acc[mi][ni] = __builtin_amdgcn_mfma_f32_16x16x32_f16(xf[mi], af[ni], acc[mi][ni], 0, 0, 0);

    __builtin_amdgcn_sched_barrier(0);
    if (it + 1 < NIT) __builtin_amdgcn_s_barrier();  // reads done before next overwrite
    buf ^= 1;
  }

  const float eps = (b_it >= NIT) ? (1.f / 2048.f) : 1.f;  // all-scaled splits
  float* outp = part + ((size_t)(split * 2 + lu_) << 20);
#pragma unroll
  for (int mi = 0; mi < 4; ++mi) {
    const int r0 = i0 + wm * 64 + mi * 16 + lhi * 4;       // C: row=(lane>>4)*4+reg
#pragma unroll
    for (int ni = 0; ni < 4; ++ni) {
      const int c = j0 + wn * 64 + ni * 16 + ln15;         // C: col=lane&15
#pragma unroll
      for (int e = 0; e < 4; ++e)
        outp[(size_t)(r0 + e) * DD + c] = acc[mi][ni][e] * eps;
    }
  }
}

// -------- fused: [blocks 0..1023] convert (reduce NS*2 partial slabs, clamp, split, bias matvec)
//                 [blocks 1024..1535] prep next layer's A planes (fp32 [k][n] -> f16 [n][k] x2)
template<int NS>
__global__ __launch_bounds__(256)
void convert_prep(int direct,
                  const float* __restrict__ xt, const float* __restrict__ part,
                  const float* __restrict__ cl, const float* __restrict__ cu,
                  _Float16* __restrict__ pl1, _Float16* __restrict__ pl2,
                  _Float16* __restrict__ nl1, _Float16* __restrict__ nl2,
                  _Float16* __restrict__ pu1, _Float16* __restrict__ pu2,
                  _Float16* __restrict__ nu1, _Float16* __restrict__ nu2,
                  float* __restrict__ bl, float* __restrict__ bu,
                  const float* __restrict__ AloN, const float* __restrict__ AupN,
                  _Float16* __restrict__ L1, _Float16* __restrict__ L2,
                  _Float16* __restrict__ U1, _Float16* __restrict__ U2)
{
  __shared__ float shmem[64][68];
  const int t = threadIdx.x;

  if (blockIdx.x < 1024) {
    const int i = blockIdx.x;
    const int k = t * 4;
    const size_t off = (size_t)i * DD + k;

    float Yl[4], Yu[4];
    if (direct) {
      const float4 y = *(const float4*)&xt[off];
      Yl[0] = Yu[0] = y.x; Yl[1] = Yu[1] = y.y; Yl[2] = Yu[2] = y.z; Yl[3] = Yu[3] = y.w;
    } else {
#pragma unroll
      for (int e = 0; e < 4; ++e) { Yl[e] = 0.f; Yu[e] = 0.f; }
#pragma unroll
      for (int s = 0; s < NS; ++s) {
        const float4 a = *(const float4*)&part[((size_t)(s * 2 + 0) << 20) + off];
        const float4 b = *(const float4*)&part[((size_t)(s * 2 + 1) << 20) + off];
        Yl[0] += a.x; Yl[1] += a.y; Yl[2] += a.z; Yl[3] += a.w;
        Yu[0] += b.x; Yu[1] += b.y; Yu[2] += b.z; Yu[3] += b.w;
      }
    }

    const float4 c4l = *(const float4*)&cl[k];
    const float4 c4u = *(const float4*)&cu[k];
    const float Cl[4] = {c4l.x, c4l.y, c4l.z, c4l.w};
    const float Cu[4] = {c4u.x, c4u.y, c4u.z, c4u.w};

    f16x4 o_pl1, o_pl2, o_nl1, o_nl2, o_pu1, o_pu2, o_nu1, o_nu2;
    float blp = 0.f, bup = 0.f;
#pragma unroll
    for (int e = 0; e < 4; ++e) {
      const float pl = fmaxf(Yl[e], 0.f), nl = fminf(Yl[e], 0.f);
      const float pu = fmaxf(Yu[e], 0.f), nu = fminf(Yu[e], 0.f);
      blp += pl * Cl[e] + nl * Cu[e];
      bup += pu * Cu[e] + nu * Cl[e];
      _Float16 h;
      h = (_Float16)pl; o_pl1[e] = h; o_pl2[e] = (_Float16)((pl - (float)h) * 2048.f);
      h = (_Float16)nl; o_nl1[e] = h; o_nl2[e] = (_Float16)((nl - (float)h) * 2048.f);
      h = (_Float16)pu; o_pu1[e] = h; o_pu2[e] = (_Float16)((pu - (float)h) * 2048.f);
      h = (_Float16)nu; o_nu1[e] = h; o_nu2[e] = (_Float16)((nu - (float)h) * 2048.f);
    }
    *(f16x4*)&pl1[off] = o_pl1;  *(f16x4*)&pl2[off] = o_pl2;
    *(f16x4*)&nl1[off] = o_nl1;  *(f16x4*)&nl2[off] = o_nl2;
    *(f16x4*)&pu1[off] = o_pu1;  *(f16x4*)&pu2[off] = o_pu2;
    *(f16x4*)&nu1[off] = o_nu1;  *(f16x4*)&nu2[off] = o_nu2;

#pragma unroll
    for (int o = 32; o > 0; o >>= 1) {
      blp += __shfl_down(blp, o, 64);
      bup += __shfl_down(bup, o, 64);
    }
    if ((t & 63) == 0) { shmem[0][t >> 6] = blp; shmem[1][t >> 6] = bup; }
    __syncthreads();
    if (t == 0) {
      bl[i] += shmem[0][0] + shmem[0][1] + shmem[0][2] + shmem[0][3];
      bu[i] += shmem[1][0] + shmem[1][1] + shmem[1][2] + shmem[1][3];
    }
  } else {
    const int r = blockIdx.x - 1024;         // 0..511
    const int k0 = (r & 15) * 64;
    const int n0 = ((r >> 4) & 15) * 64;
    const int zz = r >> 8;                   // 0: lo, 1: up
    const int rid = t >> 4, cid = t & 15;
    const float* src = zz ? AupN : AloN;
    _Float16* d1 = zz ? U1 : L1;
    _Float16* d2 = zz ? U2 : L2;
#pragma unroll
    for (int rr = 0; rr < 4; ++rr) {
      const int kk = rid * 4 + rr;
      *(float4*)&shmem[kk][cid * 4] = *(const float4*)&src[(size_t)(k0 + kk) * DD + n0 + cid * 4];
    }
    __syncthreads();
#pragma unroll
    for (int rr = 0; rr < 4; ++rr) {
      const int n = rid * 4 + rr;
      f16x4 v1, v2;
#pragma unroll
      for (int e = 0; e < 4; ++e) {
        const float v = shmem[cid * 4 + e][n];
        const _Float16 h = (_Float16)v;
        v1[e] = h;
        v2[e] = (_Float16)((v - (float)h) * 2048.f);
      }
      const size_t o = (size_t)(n0 + n) * DD + k0 + cid * 4;
      *(f16x4*)&d1[o] = v1;
      *(f16x4*)&d2[o] = v2;
    }
  }
}

// -------- init: W -> W^T (fp32) --------
__global__ __launch_bounds__(256)
void transpose_w(const float* __restrict__ W, float* __restrict__ xt)
{
  __shared__ float tile[32][33];
  const int x  = blockIdx.x * 32 + threadIdx.x;
  const int y0 = blockIdx.y * 32 + threadIdx.y;
#pragma unroll
  for (int r = 0; r < 32; r += 8)
    tile[threadIdx.y + r][threadIdx.x] = W[(size_t)(y0 + r) * DD + x];
  __syncthreads();
  const int xo  = blockIdx.y * 32 + threadIdx.x;
  const int yo0 = blockIdx.x * 32 + threadIdx.y;
#pragma unroll
  for (int r = 0; r < 32; r += 8)
    xt[(size_t)(yo0 + r) * DD + xo] = tile[threadIdx.x][threadIdx.y + r];
}

// -------- final: reduce partials, concretize with input box --------
template<int NS>
__global__ __launch_bounds__(256)
void bs_final2(const float* __restrict__ part,
               const float* __restrict__ bl, const float* __restrict__ bu,
               const float* __restrict__ inLo, const float* __restrict__ inUp,
               float* __restrict__ out)
{
  const int i = blockIdx.x;
  const int t = threadIdx.x;
  const int k = t * 4;
  const size_t off = (size_t)i * DD + k;
  float Xl[4] = {0.f, 0.f, 0.f, 0.f}, Xu[4] = {0.f, 0.f, 0.f, 0.f};
#pragma unroll
  for (int s = 0; s < NS; ++s) {
    const float4 a = *(const float4*)&part[((size_t)(s * 2 + 0) << 20) + off];
    const float4 b = *(const float4*)&part[((size_t)(s * 2 + 1) << 20) + off];
    Xl[0] += a.x; Xl[1] += a.y; Xl[2] += a.z; Xl[3] += a.w;
    Xu[0] += b.x; Xu[1] += b.y; Xu[2] += b.z; Xu[3] += b.w;
  }
  const float4 lo4 = *(const float4*)&inLo[k];
  const float4 up4 = *(const float4*)&inUp[k];
  const float Lo[4] = {lo4.x, lo4.y, lo4.z, lo4.w};
  const float Up[4] = {up4.x, up4.y, up4.z, up4.w};
  float sl = 0.f, su = 0.f;
#pragma unroll
  for (int e = 0; e < 4; ++e) {
    sl += fmaxf(Xl[e], 0.f) * Lo[e] + fminf(Xl[e], 0.f) * Up[e];
    su += fmaxf(Xu[e], 0.f) * Up[e] + fminf(Xu[e], 0.f) * Lo[e];
  }
#pragma unroll
  for (int o = 32; o > 0; o >>= 1) {
    sl += __shfl_down(sl, o, 64);
    su += __shfl_down(su, o, 64);
  }
  __shared__ float red[2][4];
  if ((t & 63) == 0) { red[0][t >> 6] = sl; red[1][t >> 6] = su; }
  __syncthreads();
  if (t == 0) {
    out[i]      = red[0][0] + red[0][1] + red[0][2] + red[0][3] + bl[i];
    out[DD + i] = red[1][0] + red[1][1] + red[1][2] + red[1][3] + bu[i];
  }
}

// ==================== fp32 fallback (round-1 baseline), used if ws too small ====================
#define BM 64
#define BN 64
#define BK 16
#define TM 4
#define TN 4
#define XPAD 4
#define XSTRIDE (BM + XPAD)

struct alignas(16) StepSmem {
  float xl[2][BK][XSTRIDE];
  float xu[2][BK][XSTRIDE];
  float alo[2][BK][BN];
  float aup[2][BK][BN];
  float clo[2][BK];
  float cup[2][BK];
  float bred[8][64];
};

__global__ __launch_bounds__(256)
void bs_step(const float* __restrict__ Xl, const float* __restrict__ Xu,
             float* __restrict__ Yl, float* __restrict__ Yu,
             const float* __restrict__ Alo, const float* __restrict__ Aup,
             const float* __restrict__ Clo, const float* __restrict__ Cup,
             float* __restrict__ bl, float* __restrict__ bu)
{
  __shared__ StepSmem sm;
  const int tid = threadIdx.x;
  const int tx = tid & 15;
  const int ty = tid >> 4;
  const int i0 = blockIdx.y * BM;
  const int j0 = blockIdx.x * BN;
  const bool doBias = (blockIdx.x == 0);
  const int xrow = tid >> 2;
  const int xseg = tid & 3;
  const int arow = tid >> 4;
  const int acol = (tid & 15) * 4;
  const int brow = tid & 63;
  const int bq   = tid >> 6;

  float accl[TM][TN] = {};
  float accu[TM][TN] = {};
  float blp = 0.f, bup = 0.f;
  float4 rxl, rxu, ral, rau;
  float  rc = 0.f;

  auto load_panel = [&](int kp) {
    rxl = *(const float4*)&Xl[(size_t)(i0 + xrow) * DD + kp + xseg * 4];
    rxu = *(const float4*)&Xu[(size_t)(i0 + xrow) * DD + kp + xseg * 4];
    ral = *(const float4*)&Alo[(size_t)(kp + arow) * DD + j0 + acol];
    rau = *(const float4*)&Aup[(size_t)(kp + arow) * DD + j0 + acol];
    if (tid < 32) rc = (tid < 16) ? Clo[kp + tid] : Cup[kp + tid - 16];
  };
  auto store_panel = [&](int b) {
    const float* pxl = (const float*)&rxl;
    const float* pxu = (const float*)&rxu;
#pragma unroll
    for (int s2 = 0; s2 < 4; ++s2) {
      sm.xl[b][xseg * 4 + s2][xrow] = pxl[s2];
      sm.xu[b][xseg * 4 + s2][xrow] = pxu[s2];
    }
    *(float4*)&sm.alo[b][arow][acol] = ral;
    *(float4*)&sm.aup[b][arow][acol] = rau;
    if (tid < 16)      sm.clo[b][tid] = rc;
    else if (tid < 32) sm.cup[b][tid - 16] = rc;
  };

  load_panel(0);
  store_panel(0);
  __syncthreads();

  constexpr int NP = DD / BK;
  for (int p = 0; p < NP; ++p) {
    const int buf = p & 1;
    const bool more = (p + 1 < NP);
    if (more) load_panel((p + 1) * BK);
#pragma unroll 4
    for (int k = 0; k < BK; ++k) {
      const float4 xl4 = *(const float4*)&sm.xl[buf][k][ty * TM];
      const float4 xu4 = *(const float4*)&sm.xu[buf][k][ty * TM];
      const float4 al4 = *(const float4*)&sm.alo[buf][k][tx * TN];
      const float4 au4 = *(const float4*)&sm.aup[buf][k][tx * TN];
      const float xlv[TM] = {xl4.x, xl4.y, xl4.z, xl4.w};
      const float xuv[TM] = {xu4.x, xu4.y, xu4.z, xu4.w};
      const float alv[TN] = {al4.x, al4.y, al4.z, al4.w};
      const float auv[TN] = {au4.x, au4.y, au4.z, au4.w};
#pragma unroll
      for (int m = 0; m < TM; ++m) {
        const float pl = fmaxf(xlv[m], 0.f), nl = fminf(xlv[m], 0.f);
        const float pu = fmaxf(xuv[m], 0.f), nu = fminf(xuv[m], 0.f);
#pragma unroll
        for (int n = 0; n < TN; ++n) {
          accl[m][n] = fmaf(pl, alv[n], fmaf(nl, auv[n], accl[m][n]));
          accu[m][n] = fmaf(pu, auv[n], fmaf(nu, alv[n], accu[m][n]));
        }
      }
    }
    if (doBias) {
#pragma unroll
      for (int kk = 0; kk < 4; ++kk) {
        const int k = bq * 4 + kk;
        const float xlv = sm.xl[buf][k][brow];
        const float xuv = sm.xu[buf][k][brow];
        const float cl = sm.clo[buf][k], cu = sm.cup[buf][k];
        blp += fmaxf(xlv, 0.f) * cl + fminf(xlv, 0.f) * cu;
        bup += fmaxf(xuv, 0.f) * cu + fminf(xuv, 0.f) * cl;
      }
    }
    if (more) store_panel(buf ^ 1);
    __syncthreads();
  }

#pragma unroll
  for (int m = 0; m < TM; ++m) {
    *(float4*)&Yl[(size_t)(i0 + ty * TM + m) * DD + j0 + tx * TN] =
        make_float4(accl[m][0], accl[m][1], accl[m][2], accl[m][3]);
    *(float4*)&Yu[(size_t)(i0 + ty * TM + m) * DD + j0 + tx * TN] =
        make_float4(accu[m][0], accu[m][1], accu[m][2], accu[m][3]);
  }
  if (doBias) {
    sm.bred[bq][brow]     = blp;
    sm.bred[4 + bq][brow] = bup;
    __syncthreads();
    if (tid < 64) {
      const int i = i0 + tid;
      bl[i] += sm.bred[0][tid] + sm.bred[1][tid] + sm.bred[2][tid] + sm.bred[3][tid];
      bu[i] += sm.bred[4][tid] + sm.bred[5][tid] + sm.bred[6][tid] + sm.bred[7][tid];
    }
  }
}

__global__ __launch_bounds__(256)
void bs_transpose_init(const float* __restrict__ W,
                       float* __restrict__ xl, float* __restrict__ xu)
{
  __shared__ float tile[32][33];
  const int x  = blockIdx.x * 32 + threadIdx.x;
  const int y0 = blockIdx.y * 32 + threadIdx.y;
#pragma unroll
  for (int r = 0; r < 32; r += 8)
    tile[threadIdx.y + r][threadIdx.x] = W[(size_t)(y0 + r) * DD + x];
  __syncthreads();
  const int xo  = blockIdx.y * 32 + threadIdx.x;
  const int yo0 = blockIdx.x * 32 + threadIdx.y;
#pragma unroll
  for (int r = 0; r < 32; r += 8) {
    const float v = tile[threadIdx.x][threadIdx.y + r];
    xl[(size_t)(yo0 + r) * DD + xo] = v;
    xu[(size_t)(yo0 + r) * DD + xo] = v;
  }
}

__global__ __launch_bounds__(256)
void bs_final(const float* __restrict__ Xl, const float* __restrict__ Xu,
              const float* __restrict__ bl, const float* __restrict__ bu,
              const float* __restrict__ inLo, const float* __restrict__ inUp,
              float* __restrict__ out)
{
  __shared__ float red[2][4];
  const int i = blockIdx.x;
  const int tid = threadIdx.x;
  const float4 xl4 = *(const float4*)&Xl[(size_t)i * DD + tid * 4];
  const float4 xu4 = *(const float4*)&Xu[(size_t)i * DD + tid * 4];
  const float4 lo4 = *(const float4*)&inLo[tid * 4];
  const float4 up4 = *(const float4*)&inUp[tid * 4];
  const float xlv[4] = {xl4.x, xl4.y, xl4.z, xl4.w};
  const float xuv[4] = {xu4.x, xu4.y, xu4.z, xu4.w};
  const float lov[4] = {lo4.x, lo4.y, lo4.z, lo4.w};
  const float upv[4] = {up4.x, up4.y, up4.z, up4.w};
  float sl = 0.f, su = 0.f;
#pragma unroll
  for (int c = 0; c < 4; ++c) {
    sl += fmaxf(xlv[c], 0.f) * lov[c] + fminf(xlv[c], 0.f) * upv[c];
    su += fmaxf(xuv[c], 0.f) * upv[c] + fminf(xuv[c], 0.f) * lov[c];
  }
#pragma unroll
  for (int off = 32; off > 0; off >>= 1) {
    sl += __shfl_down(sl, off, 64);
    su += __shfl_down(su, off, 64);
  }
  if ((tid & 63) == 0) { red[0][tid >> 6] = sl; red[1][tid >> 6] = su; }
  __syncthreads();
  if (tid == 0) {
    out[i]      = red[0][0] + red[0][1] + red[0][2] + red[0][3] + bl[i];
    out[DD + i] = red[1][0] + red[1][1] + red[1][2] + red[1][3] + bu[i];
  }
}

// ==================== host ====================
template<int NS>
static void run_f16(const float* W, const float* biases,
                    const float* AloAll, const float* AupAll,
                    const float* CloAll, const float* CupAll,
                    const float* inLo, const float* inUp,
                    float* out, char* ws, hipStream_t stream)
{
  // layout: part (NS*2 x 4 MB) | X planes (16 MB) | A planes (8 MB) | biases
  // XT aliased into part slab 0 (only live before the first gemm).
  float*     part = (float*)ws;
  _Float16*  xpl  = (_Float16*)(ws + ((size_t)NS * 8ull << 20));
  _Float16*  apl  = (_Float16*)(ws + (((size_t)NS * 8ull + 16) << 20));
  float*     bl   = (float*)(ws + (((size_t)NS * 8ull + 24) << 20));
  float*     bu   = bl + DD;
  float*     XT   = part;

  auto P = [&](int idx) { return xpl + (size_t)idx * (1u << 20); };
  _Float16 *pl1 = P(0), *pl2 = P(1), *nl1 = P(2), *nl2 = P(3);
  _Float16 *pu1 = P(4), *pu2 = P(5), *nu1 = P(6), *nu2 = P(7);
  _Float16 *AL1 = apl, *AL2 = apl + (1u << 20), *AU1 = apl + (2u << 20), *AU2 = apl + (3u << 20);

  GemmTabs tabs;
  // lu=0 (xl'): scaled group first (K<4096): pl1*AL2', pl2'*AL1, nl1*AU2', nl2'*AU1 ; then pl1*AL1, nl1*AU1
  const _Float16* xs0[6] = {pl1, pl2, nl1, nl2, pl1, nl1};
  const _Float16* as0[6] = {AL2, AL1, AU2, AU1, AL1, AU1};
  // lu=1 (xu'): pu1*AU2', pu2'*AU1, nu1*AL2', nu2'*AL1 ; then pu1*AU1, nu1*AL1
  const _Float16* xs1[6] = {pu1, pu2, nu1, nu2, pu1, nu1};
  const _Float16* as1[6] = {AU2, AU1, AL2, AL1, AU1, AL1};
  for (int s = 0; s < 6; ++s) {
    tabs.xs[0][s] = xs0[s]; tabs.as[0][s] = as0[s];
    tabs.xs[1][s] = xs1[s]; tabs.as[1][s] = as1[s];
  }

  transpose_w<<<dim3(32, 32), dim3(32, 8), 0, stream>>>(W, XT);
  hipMemcpyAsync(bl, biases, DD * sizeof(float), hipMemcpyDeviceToDevice, stream);
  hipMemcpyAsync(bu, biases, DD * sizeof(float), hipMemcpyDeviceToDevice, stream);

  convert_prep<NS><<<1536, 256, 0, stream>>>(1, XT, part, CloAll, CupAll,
                                             pl1, pl2, nl1, nl2, pu1, pu2, nu1, nu2, bl, bu,
                                             AloAll, AupAll, AL1, AL2, AU1, AU2);
  for (int s = 0; s < LL; ++s) {
    gemm_step<NS><<<dim3(8, 8, 2 * NS), 256, 0, stream>>>(tabs, part);
    if (s < LL - 1)
      convert_prep<NS><<<1536, 256, 0, stream>>>(0, XT, part,
                                                 CloAll + (size_t)(s + 1) * DD,
                                                 CupAll + (size_t)(s + 1) * DD,
                                                 pl1, pl2, nl1, nl2, pu1, pu2, nu1, nu2, bl, bu,
                                                 AloAll + (size_t)(s + 1) * DD * DD,
                                                 AupAll + (size_t)(s + 1) * DD * DD,
                                                 AL1, AL2, AU1, AU2);
  }
  bs_final2<NS><<<DD, 256, 0, stream>>>(part, bl, bu, inLo, inUp, out);
}

extern "C" void kernel_launch(void* const* d_in, const int* in_sizes, int n_in,
                              void* d_out, int out_size, void* d_ws, size_t ws_size,
                              hipStream_t stream)
{
  const float* W      = (const float*)d_in[0];
  const float* biases = (const float*)d_in[1];
  const float* AloAll = (const float*)d_in[2];
  const float* AupAll = (const float*)d_in[3];
  const float* CloAll = (const float*)d_in[4];
  const float* CupAll = (const float*)d_in[5];
  const float* inLo   = (const float*)d_in[6];
  const float* inUp   = (const float*)d_in[7];
  float* out = (float*)d_out;

  const size_t NEED6 = (72ull << 20) + 8192;   // 48 part + 16 X + 8 A + biases
  const size_t NEED4 = (56ull << 20) + 8192;   // 32 part + 16 X + 8 A + biases

  if (ws_size >= NEED6) {
    run_f16<6>(W, biases, AloAll, AupAll, CloAll, CupAll, inLo, inUp, out, (char*)d_ws, stream);
    return;
  }
  if (ws_size >= NEED4) {
    run_f16<4>(W, biases, AloAll, AupAll, CloAll, CupAll, inLo, inUp, out, (char*)d_ws, stream);
    return;
  }

  // ---------- fp32 fallback ----------
  float* ws  = (float*)d_ws;
  float* XA  = ws;
  float* XuA = ws + (size_t)DD * DD;
  float* XB  = ws + 2ull * DD * DD;
  float* XuB = ws + 3ull * DD * DD;
  float* bl  = ws + 4ull * DD * DD;
  float* bu  = bl + DD;
  bs_transpose_init<<<dim3(DD / 32, DD / 32), dim3(32, 8), 0, stream>>>(W, XA, XuA);
  hipMemcpyAsync(bl, biases, DD * sizeof(float), hipMemcpyDeviceToDevice, stream);
  hipMemcpyAsync(bu, biases, DD * sizeof(float), hipMemcpyDeviceToDevice, stream);
  const float* xi  = XA;  const float* xui = XuA;
  float*       xo  = XB;  float*       xuo = XuB;
  for (int l = 0; l < LL; ++l) {
    bs_step<<<dim3(DD / BN, DD / BM), 256, 0, stream>>>(
        xi, xui, xo, xuo,
        AloAll + (size_t)l * DD * DD, AupAll + (size_t)l * DD * DD,
        CloAll + (size_t)l * DD,      CupAll + (size_t)l * DD, bl, bu);
    const float* txi = xi; const float* txui = xui;
    xi = xo; xui = xuo;
    xo = (float*)txi; xuo = (float*)txui;
  }
  bs_final<<<DD, 256, 0, stream>>>(xi, xui, bl, bu, inLo, inUp, out);
}

// Round 7
// 993.129 us; speedup vs baseline: 1.2180x; 1.2180x over previous
//
#include <hip/hip_runtime.h>

// DeepPoly backsubstitution, MI355X. Round 7: 256x128-tile ring-3 pipelined MFMA kernel.
//
// K-loop per tile t (K-tile = 64):
//   stage6(t+2 -> slot (t+2)%3)   // 6 global_load_lds per wave; slot's readers done at t-1's barrier
//   s_waitcnt vmcnt(12)           // tile t's 6 loads landed (t+1's 6 + t+2's 6 still in flight)
//   s_barrier                     // all waves: tile t ready
//   16 ds_read_b128 + 32 MFMA (compiler-scheduled lgkmcnt), setprio(1) around MFMA
//   s_barrier                     // readers done before anyone stages into slot t%3 (at t+1)
// No vmcnt(0)/lgkmcnt(0) drain in the loop. 8 waves, 1 block/CU, 144 KB dynamic LDS.

#define DD 1024
#define LL 16

typedef _Float16 f16x8 __attribute__((ext_vector_type(8)));
typedef _Float16 f16x4 __attribute__((ext_vector_type(4)));
typedef float f32x4 __attribute__((ext_vector_type(4)));

__device__ __forceinline__ void gload16(const void* gsrc, void* ldst) {
  __builtin_amdgcn_global_load_lds(
      (const __attribute__((address_space(1))) unsigned int*)gsrc,
      (__attribute__((address_space(3))) unsigned int*)ldst, 16, 0, 0);
}

struct GemmTabs {
  const _Float16* xs[2][6];
  const _Float16* as[2][6];
};

// ---------------- ring-3 pipelined GEMM: 256x128 tile, BK=64, 8 waves ----------------
struct SM8 {
  _Float16 x[3][32][512];   // [slot][frag = mf*2+kc][512]  96 KB  (X: 256 rows)
  _Float16 a[3][16][512];   // [slot][frag = nf*2+kc][512]  48 KB  (A: 128 rows [n][k])
};

__global__ __launch_bounds__(512, 2)
void gemm_step8(GemmTabs tabs, float* __restrict__ part)
{
  extern __shared__ char dynsm[];
  SM8& sm = *reinterpret_cast<SM8*>(dynsm);

  const int tid  = threadIdx.x;
  const int w    = tid >> 6;         // 0..7
  const int lane = tid & 63;
  const int ln15 = lane & 15;
  const int lhi  = lane >> 4;
  const int wm   = w >> 1;           // 0..3  (m quadrant, 64 rows)
  const int wn   = w & 1;            // 0..1  (n half, 64 cols)

  // grid 256: xcd = lin&7 = (lu,split) slice; 32 (i,j) tiles within the XCD.
  const int lin = blockIdx.x;
  const int zz  = lin & 7;
  const int ij  = lin >> 3;          // 0..31
  const int i0  = (ij >> 3) * 256;
  const int j0  = (ij & 7) * 128;
  const int lu    = zz >> 2;
  const int split = zz & 3;

  constexpr int NT = 24;             // 1536 K per split, K-tile 64
  const int kbase = split * 1536;
  const int seg0  = kbase >> 10;
  const int seg1  = (seg0 + 1 < 6) ? seg0 + 1 : 5;
  const int it_sw = (((seg0 + 1) << 10) - kbase) >> 6;   // tile idx of segment switch
  const _Float16* xpA = tabs.xs[lu][seg0];
  const _Float16* apA = tabs.as[lu][seg0];
  const _Float16* xpB = tabs.xs[lu][seg1];
  const _Float16* apB = tabs.as[lu][seg1];
  const int b_it = (4096 - kbase) >> 6;                  // scale-group boundary tile

  f32x4 acc[4][4];
#pragma unroll
  for (int a = 0; a < 4; ++a)
#pragma unroll
    for (int b = 0; b < 4; ++b) acc[a][b] = (f32x4){0.f, 0.f, 0.f, 0.f};

  auto stage6 = [&](int slot, int t) {
    const _Float16* xp = (t < it_sw) ? xpA : xpB;
    const _Float16* ap = (t < it_sw) ? apA : apB;
    const int kcol = ((kbase + t * 64) & 1023) + lhi * 8;
#pragma unroll
    for (int r = 0; r < 6; ++r) {
      const int g = r * 8 + w;       // 0..47, wave-uniform
      if (g < 32) {                  // X frag: mf = g>>1, kc = g&1
        gload16(xp + (size_t)(i0 + (g >> 1) * 16 + ln15) * DD + kcol + (g & 1) * 32,
                &sm.x[slot][g][0]);
      } else {                       // A frag: nf = (g-32)>>1, kc = (g-32)&1
        const int gg = g - 32;
        gload16(ap + (size_t)(j0 + (gg >> 1) * 16 + ln15) * DD + kcol + (gg & 1) * 32,
                &sm.a[slot][gg][0]);
      }
    }
  };

  stage6(0, 0);
  stage6(1, 1);                      // 12 loads in flight per wave

  int cur = 0;
#pragma unroll 1
  for (int t = 0; t < NT; ++t) {
    if (t + 2 < NT) {
      int s2 = cur + 2; if (s2 >= 3) s2 -= 3;
      stage6(s2, t + 2);             // 18 in flight
      asm volatile("s_waitcnt vmcnt(12)" ::: "memory");  // tile t landed (this wave)
    } else if (t + 2 == NT) {
      asm volatile("s_waitcnt vmcnt(6)" ::: "memory");
    } else {
      asm volatile("s_waitcnt vmcnt(0)" ::: "memory");
    }
    __builtin_amdgcn_s_barrier();    // tile t landed (all waves)
    __builtin_amdgcn_sched_barrier(0);

    if (t == b_it) {                 // scaled K-group done: acc *= 2^-11
#pragma unroll
      for (int a = 0; a < 4; ++a)
#pragma unroll
        for (int b = 0; b < 4; ++b) acc[a][b] *= (1.f / 2048.f);
    }

    f16x8 xf[2][4], af[2][4];
#pragma unroll
    for (int kc = 0; kc < 2; ++kc) {
#pragma unroll
      for (int mi = 0; mi < 4; ++mi)
        xf[kc][mi] = *(const f16x8*)&sm.x[cur][(wm * 4 + mi) * 2 + kc][lane * 8];
#pragma unroll
      for (int ni = 0; ni < 4; ++ni)
        af[kc][ni] = *(const f16x8*)&sm.a[cur][(wn * 4 + ni) * 2 + kc][lane * 8];
    }
    __builtin_amdgcn_s_setprio(1);
#pragma unroll
    for (int kc = 0; kc < 2; ++kc)
#pragma unroll
      for (int mi = 0; mi < 4; ++mi)
#pragma unroll
        for (int ni = 0; ni < 4; ++ni)
          acc[mi][ni] = __builtin_amdgcn_mfma_f32_16x16x32_f16(xf[kc][mi], af[kc][ni], acc[mi][ni], 0, 0, 0);
    __builtin_amdgcn_s_setprio(0);

    __builtin_amdgcn_sched_barrier(0);
    __builtin_amdgcn_s_barrier();    // readers of slot cur done before t+1 stages into it
    cur = (cur == 2) ? 0 : cur + 1;
  }

  const float eps = (b_it >= NT) ? (1.f / 2048.f) : 1.f;  // all-scaled splits
  float* outp = part + ((size_t)(split * 2 + lu) << 20);
#pragma unroll
  for (int mi = 0; mi < 4; ++mi) {
    const int r0 = i0 + wm * 64 + mi * 16 + lhi * 4;      // C: row=(lane>>4)*4+reg
#pragma unroll
    for (int ni = 0; ni < 4; ++ni) {
      const int c = j0 + wn * 64 + ni * 16 + ln15;        // C: col=lane&15
#pragma unroll
      for (int e = 0; e < 4; ++e)
        outp[(size_t)(r0 + e) * DD + c] = acc[mi][ni][e] * eps;
    }
  }
}

// ---------------- fallback 2-phase GEMM (round-6), used if dyn-LDS attr fails ----------------
template<int NSPLIT>
__global__ __launch_bounds__(256)
void gemm_step(GemmTabs tabs, float* __restrict__ part)
{
  constexpr int KSPL = 6144 / NSPLIT;
  constexpr int NIT  = KSPL / 32;
  constexpr int NZ   = 2 * NSPLIT;

  __shared__ _Float16 smX[2][8][512];
  __shared__ _Float16 smA[2][8][512];

  const int tid  = threadIdx.x;
  const int w    = tid >> 6;
  const int lane = tid & 63;
  const int ln15 = lane & 15;
  const int lhi  = lane >> 4;

  const int lin = blockIdx.x + gridDim.x * (blockIdx.y + gridDim.y * blockIdx.z);
  const int zz  = lin % NZ;
  const int ij  = lin / NZ;
  const int j0  = (ij & 7) * 128;
  const int i0  = (ij >> 3) * 128;
  const int lu_   = zz / NSPLIT;
  const int split = zz % NSPLIT;

  const _Float16* const* xtab = tabs.xs[lu_];
  const _Float16* const* atab = tabs.as[lu_];

  const int wm = w >> 1, wn = w & 1;

  const int kbase = split * KSPL;
  const int seg0  = kbase >> 10;
  const int segB_ = (seg0 + 1 < 6) ? seg0 + 1 : 5;
  const int it_sw = (((seg0 + 1) << 10) - kbase) >> 5;
  const _Float16* xpA = xtab[seg0];
  const _Float16* apA = atab[seg0];
  const _Float16* xpB = xtab[segB_];
  const _Float16* apB = atab[segB_];

  f32x4 acc[4][4];
#pragma unroll
  for (int a = 0; a < 4; ++a)
#pragma unroll
    for (int b = 0; b < 4; ++b) acc[a][b] = (f32x4){0.f, 0.f, 0.f, 0.f};

  const int b_it = (4096 - kbase) >> 5;

  auto stage = [&](int buf, int it) {
    const _Float16* xp = (it < it_sw) ? xpA : xpB;
    const _Float16* ap = (it < it_sw) ? apA : apB;
    const int kcol = ((kbase + it * 32) & 1023) + lhi * 8;
#pragma unroll
    for (int r = 0; r < 4; ++r) {
      const int f = r * 4 + w;
      if (f < 8)
        gload16(xp + (size_t)(i0 + f * 16 + ln15) * DD + kcol, &smX[buf][f & 7][0]);
      else
        gload16(ap + (size_t)(j0 + (f - 8) * 16 + ln15) * DD + kcol, &smA[buf][f & 7][0]);
    }
  };

  stage(0, 0);

  int buf = 0;
  for (int it = 0; it < NIT; ++it) {
    if (it + 1 < NIT) {
      stage(buf ^ 1, it + 1);
      asm volatile("s_waitcnt vmcnt(4)" ::: "memory");
    } else {
      asm volatile("s_waitcnt vmcnt(0)" ::: "memory");
    }
    __builtin_amdgcn_s_barrier();
    __builtin_amdgcn_sched_barrier(0);

    if (it == b_it) {
#pragma unroll
      for (int a = 0; a < 4; ++a)
#pragma unroll
        for (int b = 0; b < 4; ++b) acc[a][b] *= (1.f / 2048.f);
    }

    f16x8 xf[4], af[4];
#pragma unroll
    for (int mi = 0; mi < 4; ++mi)
      xf[mi] = *(const f16x8*)&smX[buf][wm * 4 + mi][lane * 8];
#pragma unroll
    for (int ni = 0; ni < 4; ++ni)
      af[ni] = *(const f16x8*)&smA[buf][wn * 4 + ni][lane * 8];
#pragma unroll
    for (int mi = 0; mi < 4; ++mi)
#pragma unroll
      for (int ni = 0; ni < 4; ++ni)
        acc[mi][ni] = __builtin_amdgcn_mfma_f32_16x16x32_f16(xf[mi], af[ni], acc[mi][ni], 0, 0, 0);

    __builtin_amdgcn_sched_barrier(0);
    if (it + 1 < NIT) __builtin_amdgcn_s_barrier();
    buf ^= 1;
  }

  const float eps = (b_it >= NIT) ? (1.f / 2048.f) : 1.f;
  float* outp = part + ((size_t)(split * 2 + lu_) << 20);
#pragma unroll
  for (int mi = 0; mi < 4; ++mi) {
    const int r0 = i0 + wm * 64 + mi * 16 + lhi * 4;
#pragma unroll
    for (int ni = 0; ni < 4; ++ni) {
      const int c = j0 + wn * 64 + ni * 16 + ln15;
#pragma unroll
      for (int e = 0; e < 4; ++e)
        outp[(size_t)(r0 + e) * DD + c] = acc[mi][ni][e] * eps;
    }
  }
}

// -------- fused: [0..1023] convert (reduce NS*2 slabs, clamp, split, bias matvec)
//                 [1024..1535] prep next layer's A planes --------
template<int NS>
__global__ __launch_bounds__(256)
void convert_prep(int direct,
                  const float* __restrict__ xt, const float* __restrict__ part,
                  const float* __restrict__ cl, const float* __restrict__ cu,
                  _Float16* __restrict__ pl1, _Float16* __restrict__ pl2,
                  _Float16* __restrict__ nl1, _Float16* __restrict__ nl2,
                  _Float16* __restrict__ pu1, _Float16* __restrict__ pu2,
                  _Float16* __restrict__ nu1, _Float16* __restrict__ nu2,
                  float* __restrict__ bl, float* __restrict__ bu,
                  const float* __restrict__ AloN, const float* __restrict__ AupN,
                  _Float16* __restrict__ L1, _Float16* __restrict__ L2,
                  _Float16* __restrict__ U1, _Float16* __restrict__ U2)
{
  __shared__ float shmem[64][68];
  const int t = threadIdx.x;

  if (blockIdx.x < 1024) {
    const int i = blockIdx.x;
    const int k = t * 4;
    const size_t off = (size_t)i * DD + k;

    float Yl[4], Yu[4];
    if (direct) {
      const float4 y = *(const float4*)&xt[off];
      Yl[0] = Yu[0] = y.x; Yl[1] = Yu[1] = y.y; Yl[2] = Yu[2] = y.z; Yl[3] = Yu[3] = y.w;
    } else {
#pragma unroll
      for (int e = 0; e < 4; ++e) { Yl[e] = 0.f; Yu[e] = 0.f; }
#pragma unroll
      for (int s = 0; s < NS; ++s) {
        const float4 a = *(const float4*)&part[((size_t)(s * 2 + 0) << 20) + off];
        const float4 b = *(const float4*)&part[((size_t)(s * 2 + 1) << 20) + off];
        Yl[0] += a.x; Yl[1] += a.y; Yl[2] += a.z; Yl[3] += a.w;
        Yu[0] += b.x; Yu[1] += b.y; Yu[2] += b.z; Yu[3] += b.w;
      }
    }

    const float4 c4l = *(const float4*)&cl[k];
    const float4 c4u = *(const float4*)&cu[k];
    const float Cl[4] = {c4l.x, c4l.y, c4l.z, c4l.w};
    const float Cu[4] = {c4u.x, c4u.y, c4u.z, c4u.w};

    f16x4 o_pl1, o_pl2, o_nl1, o_nl2, o_pu1, o_pu2, o_nu1, o_nu2;
    float blp = 0.f, bup = 0.f;
#pragma unroll
    for (int e = 0; e < 4; ++e) {
      const float pl = fmaxf(Yl[e], 0.f), nl = fminf(Yl[e], 0.f);
      const float pu = fmaxf(Yu[e], 0.f), nu = fminf(Yu[e], 0.f);
      blp += pl * Cl[e] + nl * Cu[e];
      bup += pu * Cu[e] + nu * Cl[e];
      _Float16 h;
      h = (_Float16)pl; o_pl1[e] = h; o_pl2[e] = (_Float16)((pl - (float)h) * 2048.f);
      h = (_Float16)nl; o_nl1[e] = h; o_nl2[e] = (_Float16)((nl - (float)h) * 2048.f);
      h = (_Float16)pu; o_pu1[e] = h; o_pu2[e] = (_Float16)((pu - (float)h) * 2048.f);
      h = (_Float16)nu; o_nu1[e] = h; o_nu2[e] = (_Float16)((nu - (float)h) * 2048.f);
    }
    *(f16x4*)&pl1[off] = o_pl1;  *(f16x4*)&pl2[off] = o_pl2;
    *(f16x4*)&nl1[off] = o_nl1;  *(f16x4*)&nl2[off] = o_nl2;
    *(f16x4*)&pu1[off] = o_pu1;  *(f16x4*)&pu2[off] = o_pu2;
    *(f16x4*)&nu1[off] = o_nu1;  *(f16x4*)&nu2[off] = o_nu2;

#pragma unroll
    for (int o = 32; o > 0; o >>= 1) {
      blp += __shfl_down(blp, o, 64);
      bup += __shfl_down(bup, o, 64);
    }
    if ((t & 63) == 0) { shmem[0][t >> 6] = blp; shmem[1][t >> 6] = bup; }
    __syncthreads();
    if (t == 0) {
      bl[i] += shmem[0][0] + shmem[0][1] + shmem[0][2] + shmem[0][3];
      bu[i] += shmem[1][0] + shmem[1][1] + shmem[1][2] + shmem[1][3];
    }
  } else {
    const int r = blockIdx.x - 1024;
    const int k0 = (r & 15) * 64;
    const int n0 = ((r >> 4) & 15) * 64;
    const int zz = r >> 8;
    const int rid = t >> 4, cid = t & 15;
    const float* src = zz ? AupN : AloN;
    _Float16* d1 = zz ? U1 : L1;
    _Float16* d2 = zz ? U2 : L2;
#pragma unroll
    for (int rr = 0; rr < 4; ++rr) {
      const int kk = rid * 4 + rr;
      *(float4*)&shmem[kk][cid * 4] = *(const float4*)&src[(size_t)(k0 + kk) * DD + n0 + cid * 4];
    }
    __syncthreads();
#pragma unroll
    for (int rr = 0; rr < 4; ++rr) {
      const int n = rid * 4 + rr;
      f16x4 v1, v2;
#pragma unroll
      for (int e = 0; e < 4; ++e) {
        const float v = shmem[cid * 4 + e][n];
        const _Float16 h = (_Float16)v;
        v1[e] = h;
        v2[e] = (_Float16)((v - (float)h) * 2048.f);
      }
      const size_t o = (size_t)(n0 + n) * DD + k0 + cid * 4;
      *(f16x4*)&d1[o] = v1;
      *(f16x4*)&d2[o] = v2;
    }
  }
}

// -------- init: W -> W^T (fp32) --------
__global__ __launch_bounds__(256)
void transpose_w(const float* __restrict__ W, float* __restrict__ xt)
{
  __shared__ float tile[32][33];
  const int x  = blockIdx.x * 32 + threadIdx.x;
  const int y0 = blockIdx.y * 32 + threadIdx.y;
#pragma unroll
  for (int r = 0; r < 32; r += 8)
    tile[threadIdx.y + r][threadIdx.x] = W[(size_t)(y0 + r) * DD + x];
  __syncthreads();
  const int xo  = blockIdx.y * 32 + threadIdx.x;
  const int yo0 = blockIdx.x * 32 + threadIdx.y;
#pragma unroll
  for (int r = 0; r < 32; r += 8)
    xt[(size_t)(yo0 + r) * DD + xo] = tile[threadIdx.x][threadIdx.y + r];
}

// -------- final: reduce partials, concretize with input box --------
template<int NS>
__global__ __launch_bounds__(256)
void bs_final2(const float* __restrict__ part,
               const float* __restrict__ bl, const float* __restrict__ bu,
               const float* __restrict__ inLo, const float* __restrict__ inUp,
               float* __restrict__ out)
{
  const int i = blockIdx.x;
  const int t = threadIdx.x;
  const int k = t * 4;
  const size_t off = (size_t)i * DD + k;
  float Xl[4] = {0.f, 0.f, 0.f, 0.f}, Xu[4] = {0.f, 0.f, 0.f, 0.f};
#pragma unroll
  for (int s = 0; s < NS; ++s) {
    const float4 a = *(const float4*)&part[((size_t)(s * 2 + 0) << 20) + off];
    const float4 b = *(const float4*)&part[((size_t)(s * 2 + 1) << 20) + off];
    Xl[0] += a.x; Xl[1] += a.y; Xl[2] += a.z; Xl[3] += a.w;
    Xu[0] += b.x; Xu[1] += b.y; Xu[2] += b.z; Xu[3] += b.w;
  }
  const float4 lo4 = *(const float4*)&inLo[k];
  const float4 up4 = *(const float4*)&inUp[k];
  const float Lo[4] = {lo4.x, lo4.y, lo4.z, lo4.w};
  const float Up[4] = {up4.x, up4.y, up4.z, up4.w};
  float sl = 0.f, su = 0.f;
#pragma unroll
  for (int e = 0; e < 4; ++e) {
    sl += fmaxf(Xl[e], 0.f) * Lo[e] + fminf(Xl[e], 0.f) * Up[e];
    su += fmaxf(Xu[e], 0.f) * Up[e] + fminf(Xu[e], 0.f) * Lo[e];
  }
#pragma unroll
  for (int o = 32; o > 0; o >>= 1) {
    sl += __shfl_down(sl, o, 64);
    su += __shfl_down(su, o, 64);
  }
  __shared__ float red[2][4];
  if ((t & 63) == 0) { red[0][t >> 6] = sl; red[1][t >> 6] = su; }
  __syncthreads();
  if (t == 0) {
    out[i]      = red[0][0] + red[0][1] + red[0][2] + red[0][3] + bl[i];
    out[DD + i] = red[1][0] + red[1][1] + red[1][2] + red[1][3] + bu[i];
  }
}

// ==================== fp32 fallback (round-1 baseline), used if ws too small ====================
#define BM 64
#define BN 64
#define BK 16
#define TM 4
#define TN 4
#define XPAD 4
#define XSTRIDE (BM + XPAD)

struct alignas(16) StepSmem {
  float xl[2][BK][XSTRIDE];
  float xu[2][BK][XSTRIDE];
  float alo[2][BK][BN];
  float aup[2][BK][BN];
  float clo[2][BK];
  float cup[2][BK];
  float bred[8][64];
};

__global__ __launch_bounds__(256)
void bs_step(const float* __restrict__ Xl, const float* __restrict__ Xu,
             float* __restrict__ Yl, float* __restrict__ Yu,
             const float* __restrict__ Alo, const float* __restrict__ Aup,
             const float* __restrict__ Clo, const float* __restrict__ Cup,
             float* __restrict__ bl, float* __restrict__ bu)
{
  __shared__ StepSmem sm;
  const int tid = threadIdx.x;
  const int tx = tid & 15;
  const int ty = tid >> 4;
  const int i0 = blockIdx.y * BM;
  const int j0 = blockIdx.x * BN;
  const bool doBias = (blockIdx.x == 0);
  const int xrow = tid >> 2;
  const int xseg = tid & 3;
  const int arow = tid >> 4;
  const int acol = (tid & 15) * 4;
  const int brow = tid & 63;
  const int bq   = tid >> 6;

  float accl[TM][TN] = {};
  float accu[TM][TN] = {};
  float blp = 0.f, bup = 0.f;
  float4 rxl, rxu, ral, rau;
  float  rc = 0.f;

  auto load_panel = [&](int kp) {
    rxl = *(const float4*)&Xl[(size_t)(i0 + xrow) * DD + kp + xseg * 4];
    rxu = *(const float4*)&Xu[(size_t)(i0 + xrow) * DD + kp + xseg * 4];
    ral = *(const float4*)&Alo[(size_t)(kp + arow) * DD + j0 + acol];
    rau = *(const float4*)&Aup[(size_t)(kp + arow) * DD + j0 + acol];
    if (tid < 32) rc = (tid < 16) ? Clo[kp + tid] : Cup[kp + tid - 16];
  };
  auto store_panel = [&](int b) {
    const float* pxl = (const float*)&rxl;
    const float* pxu = (const float*)&rxu;
#pragma unroll
    for (int s2 = 0; s2 < 4; ++s2) {
      sm.xl[b][xseg * 4 + s2][xrow] = pxl[s2];
      sm.xu[b][xseg * 4 + s2][xrow] = pxu[s2];
    }
    *(float4*)&sm.alo[b][arow][acol] = ral;
    *(float4*)&sm.aup[b][arow][acol] = rau;
    if (tid < 16)      sm.clo[b][tid] = rc;
    else if (tid < 32) sm.cup[b][tid - 16] = rc;
  };

  load_panel(0);
  store_panel(0);
  __syncthreads();

  constexpr int NP = DD / BK;
  for (int p = 0; p < NP; ++p) {
    const int buf = p & 1;
    const bool more = (p + 1 < NP);
    if (more) load_panel((p + 1) * BK);
#pragma unroll 4
    for (int k = 0; k < BK; ++k) {
      const float4 xl4 = *(const float4*)&sm.xl[buf][k][ty * TM];
      const float4 xu4 = *(const float4*)&sm.xu[buf][k][ty * TM];
      const float4 al4 = *(const float4*)&sm.alo[buf][k][tx * TN];
      const float4 au4 = *(const float4*)&sm.aup[buf][k][tx * TN];
      const float xlv[TM] = {xl4.x, xl4.y, xl4.z, xl4.w};
      const float xuv[TM] = {xu4.x, xu4.y, xu4.z, xu4.w};
      const float alv[TN] = {al4.x, al4.y, al4.z, al4.w};
      const float auv[TN] = {au4.x, au4.y, au4.z, au4.w};
#pragma unroll
      for (int m = 0; m < TM; ++m) {
        const float pl = fmaxf(xlv[m], 0.f), nl = fminf(xlv[m], 0.f);
        const float pu = fmaxf(xuv[m], 0.f), nu = fminf(xuv[m], 0.f);
#pragma unroll
        for (int n = 0; n < TN; ++n) {
          accl[m][n] = fmaf(pl, alv[n], fmaf(nl, auv[n], accl[m][n]));
          accu[m][n] = fmaf(pu, auv[n], fmaf(nu, alv[n], accu[m][n]));
        }
      }
    }
    if (doBias) {
#pragma unroll
      for (int kk = 0; kk < 4; ++kk) {
        const int k = bq * 4 + kk;
        const float xlv = sm.xl[buf][k][brow];
        const float xuv = sm.xu[buf][k][brow];
        const float cl = sm.clo[buf][k], cu = sm.cup[buf][k];
        blp += fmaxf(xlv, 0.f) * cl + fminf(xlv, 0.f) * cu;
        bup += fmaxf(xuv, 0.f) * cu + fminf(xuv, 0.f) * cl;
      }
    }
    if (more) store_panel(buf ^ 1);
    __syncthreads();
  }

#pragma unroll
  for (int m = 0; m < TM; ++m) {
    *(float4*)&Yl[(size_t)(i0 + ty * TM + m) * DD + j0 + tx * TN] =
        make_float4(accl[m][0], accl[m][1], accl[m][2], accl[m][3]);
    *(float4*)&Yu[(size_t)(i0 + ty * TM + m) * DD + j0 + tx * TN] =
        make_float4(accu[m][0], accu[m][1], accu[m][2], accu[m][3]);
  }
  if (doBias) {
    sm.bred[bq][brow]     = blp;
    sm.bred[4 + bq][brow] = bup;
    __syncthreads();
    if (tid < 64) {
      const int i = i0 + tid;
      bl[i] += sm.bred[0][tid] + sm.bred[1][tid] + sm.bred[2][tid] + sm.bred[3][tid];
      bu[i] += sm.bred[4][tid] + sm.bred[5][tid] + sm.bred[6][tid] + sm.bred[7][tid];
    }
  }
}

__global__ __launch_bounds__(256)
void bs_transpose_init(const float* __restrict__ W,
                       float* __restrict__ xl, float* __restrict__ xu)
{
  __shared__ float tile[32][33];
  const int x  = blockIdx.x * 32 + threadIdx.x;
  const int y0 = blockIdx.y * 32 + threadIdx.y;
#pragma unroll
  for (int r = 0; r < 32; r += 8)
    tile[threadIdx.y + r][threadIdx.x] = W[(size_t)(y0 + r) * DD + x];
  __syncthreads();
  const int xo  = blockIdx.y * 32 + threadIdx.x;
  const int yo0 = blockIdx.x * 32 + threadIdx.y;
#pragma unroll
  for (int r = 0; r < 32; r += 8) {
    const float v = tile[threadIdx.x][threadIdx.y + r];
    xl[(size_t)(yo0 + r) * DD + xo] = v;
    xu[(size_t)(yo0 + r) * DD + xo] = v;
  }
}

__global__ __launch_bounds__(256)
void bs_final(const float* __restrict__ Xl, const float* __restrict__ Xu,
              const float* __restrict__ bl, const float* __restrict__ bu,
              const float* __restrict__ inLo, const float* __restrict__ inUp,
              float* __restrict__ out)
{
  __shared__ float red[2][4];
  const int i = blockIdx.x;
  const int tid = threadIdx.x;
  const float4 xl4 = *(const float4*)&Xl[(size_t)i * DD + tid * 4];
  const float4 xu4 = *(const float4*)&Xu[(size_t)i * DD + tid * 4];
  const float4 lo4 = *(const float4*)&inLo[tid * 4];
  const float4 up4 = *(const float4*)&inUp[tid * 4];
  const float xlv[4] = {xl4.x, xl4.y, xl4.z, xl4.w};
  const float xuv[4] = {xu4.x, xu4.y, xu4.z, xu4.w};
  const float lov[4] = {lo4.x, lo4.y, lo4.z, lo4.w};
  const float upv[4] = {up4.x, up4.y, up4.z, up4.w};
  float sl = 0.f, su = 0.f;
#pragma unroll
  for (int c = 0; c < 4; ++c) {
    sl += fmaxf(xlv[c], 0.f) * lov[c] + fminf(xlv[c], 0.f) * upv[c];
    su += fmaxf(xuv[c], 0.f) * upv[c] + fminf(xuv[c], 0.f) * lov[c];
  }
#pragma unroll
  for (int off = 32; off > 0; off >>= 1) {
    sl += __shfl_down(sl, off, 64);
    su += __shfl_down(su, off, 64);
  }
  if ((tid & 63) == 0) { red[0][tid >> 6] = sl; red[1][tid >> 6] = su; }
  __syncthreads();
  if (tid == 0) {
    out[i]      = red[0][0] + red[0][1] + red[0][2] + red[0][3] + bl[i];
    out[DD + i] = red[1][0] + red[1][1] + red[1][2] + red[1][3] + bu[i];
  }
}

// ==================== host ====================
extern "C" void kernel_launch(void* const* d_in, const int* in_sizes, int n_in,
                              void* d_out, int out_size, void* d_ws, size_t ws_size,
                              hipStream_t stream)
{
  const float* W      = (const float*)d_in[0];
  const float* biases = (const float*)d_in[1];
  const float* AloAll = (const float*)d_in[2];
  const float* AupAll = (const float*)d_in[3];
  const float* CloAll = (const float*)d_in[4];
  const float* CupAll = (const float*)d_in[5];
  const float* inLo   = (const float*)d_in[6];
  const float* inUp   = (const float*)d_in[7];
  float* out = (float*)d_out;

  const size_t NEED = (56ull << 20) + 8192;   // 32 part + 16 X + 8 A + biases (NS=4)
  if (ws_size < NEED) {
    // ---------- fp32 fallback ----------
    float* wsf = (float*)d_ws;
    float* XA  = wsf;
    float* XuA = wsf + (size_t)DD * DD;
    float* XB  = wsf + 2ull * DD * DD;
    float* XuB = wsf + 3ull * DD * DD;
    float* bl  = wsf + 4ull * DD * DD;
    float* bu  = bl + DD;
    bs_transpose_init<<<dim3(DD / 32, DD / 32), dim3(32, 8), 0, stream>>>(W, XA, XuA);
    hipMemcpyAsync(bl, biases, DD * sizeof(float), hipMemcpyDeviceToDevice, stream);
    hipMemcpyAsync(bu, biases, DD * sizeof(float), hipMemcpyDeviceToDevice, stream);
    const float* xi  = XA;  const float* xui = XuA;
    float*       xo  = XB;  float*       xuo = XuB;
    for (int l = 0; l < LL; ++l) {
      bs_step<<<dim3(DD / BN, DD / BM), 256, 0, stream>>>(
          xi, xui, xo, xuo,
          AloAll + (size_t)l * DD * DD, AupAll + (size_t)l * DD * DD,
          CloAll + (size_t)l * DD,      CupAll + (size_t)l * DD, bl, bu);
      const float* txi = xi; const float* txui = xui;
      xi = xo; xui = xuo;
      xo = (float*)txi; xuo = (float*)txui;
    }
    bs_final<<<DD, 256, 0, stream>>>(xi, xui, bl, bu, inLo, inUp, out);
    return;
  }

  // ---------- f16-split MFMA path (NS=4) ----------
  char* ws = (char*)d_ws;
  float*     part = (float*)ws;                          // 8 slabs x 4 MB = 32 MB
  _Float16*  xpl  = (_Float16*)(ws + (32ull << 20));     // 8 X planes x 2 MB
  _Float16*  apl  = (_Float16*)(ws + (48ull << 20));     // 4 A planes x 2 MB
  float*     bl   = (float*)(ws + (56ull << 20));
  float*     bu   = bl + DD;
  float*     XT   = part;                                // aliased: only live pre-gemm

  auto P = [&](int idx) { return xpl + (size_t)idx * (1u << 20); };
  _Float16 *pl1 = P(0), *pl2 = P(1), *nl1 = P(2), *nl2 = P(3);
  _Float16 *pu1 = P(4), *pu2 = P(5), *nu1 = P(6), *nu2 = P(7);
  _Float16 *AL1 = apl, *AL2 = apl + (1u << 20), *AU1 = apl + (2u << 20), *AU2 = apl + (3u << 20);

  GemmTabs tabs;
  // lu=0 (xl'): scaled group first: pl1*AL2', pl2'*AL1, nl1*AU2', nl2'*AU1 ; then pl1*AL1, nl1*AU1
  const _Float16* xs0[6] = {pl1, pl2, nl1, nl2, pl1, nl1};
  const _Float16* as0[6] = {AL2, AL1, AU2, AU1, AL1, AU1};
  // lu=1 (xu'): pu1*AU2', pu2'*AU1, nu1*AL2', nu2'*AL1 ; then pu1*AU1, nu1*AL1
  const _Float16* xs1[6] = {pu1, pu2, nu1, nu2, pu1, nu1};
  const _Float16* as1[6] = {AU2, AU1, AL2, AL1, AU1, AL1};
  for (int s = 0; s < 6; ++s) {
    tabs.xs[0][s] = xs0[s]; tabs.as[0][s] = as0[s];
    tabs.xs[1][s] = xs1[s]; tabs.as[1][s] = as1[s];
  }

  const hipError_t attr_ok = hipFuncSetAttribute(
      reinterpret_cast<const void*>(&gemm_step8),
      hipFuncAttributeMaxDynamicSharedMemorySize, (int)sizeof(SM8));

  transpose_w<<<dim3(32, 32), dim3(32, 8), 0, stream>>>(W, XT);
  hipMemcpyAsync(bl, biases, DD * sizeof(float), hipMemcpyDeviceToDevice, stream);
  hipMemcpyAsync(bu, biases, DD * sizeof(float), hipMemcpyDeviceToDevice, stream);

  convert_prep<4><<<1536, 256, 0, stream>>>(1, XT, part, CloAll, CupAll,
                                            pl1, pl2, nl1, nl2, pu1, pu2, nu1, nu2, bl, bu,
                                            AloAll, AupAll, AL1, AL2, AU1, AU2);
  for (int s = 0; s < LL; ++s) {
    if (attr_ok == hipSuccess)
      gemm_step8<<<256, 512, sizeof(SM8), stream>>>(tabs, part);
    else
      gemm_step<4><<<dim3(8, 8, 8), 256, 0, stream>>>(tabs, part);
    if (s < LL - 1)
      convert_prep<4><<<1536, 256, 0, stream>>>(0, XT, part,
                                                CloAll + (size_t)(s + 1) * DD,
                                                CupAll + (size_t)(s + 1) * DD,
                                                pl1, pl2, nl1, nl2, pu1, pu2, nu1, nu2, bl, bu,
                                                AloAll + (size_t)(s + 1) * DD * DD,
                                                AupAll + (size_t)(s + 1) * DD * DD,
                                                AL1, AL2, AU1, AU2);
  }
  bs_final2<4><<<DD, 256, 0, stream>>>(part, bl, bu, inLo, inUp, out);
}